// Round 16
// baseline (330.683 us; speedup 1.0000x reference)
//
#include <hip/hip_runtime.h>
#include <stdint.h>

#define NDIM 64
#define SCAN_ELEMS 2048   // elements per scan block (256 thr x 8)
#define NCHK 32           // edge chunks
#define NGRP 8            // node-range groups
#define RMAX 6272         // max nodes per group (ceil(50000/8)=6250)

typedef unsigned int uint;
typedef unsigned short ushort;

// round-to-nearest-even fp32 -> bf16 (pair packed into a uint)
__device__ __forceinline__ uint f2bf2(float a, float b) {
  uint ua = __float_as_uint(a);
  uint ub = __float_as_uint(b);
  ua += 0x7fffu + ((ua >> 16) & 1u);
  ub += 0x7fffu + ((ub >> 16) & 1u);
  return (ua >> 16) | (ub & 0xffff0000u);
}
__device__ __forceinline__ float bflo(uint u) { return __uint_as_float(u << 16); }
__device__ __forceinline__ float bfhi(uint u) { return __uint_as_float(u & 0xffff0000u); }

// ---------------- weight transpose (k-major) ----------------
__global__ __launch_bounds__(256) void transpose_kernel(
    const float* __restrict__ fw, const float* __restrict__ rootw,
    const float* __restrict__ lin1, const float* __restrict__ lin2,
    float* __restrict__ fwT, float* __restrict__ wrT,
    float* __restrict__ w1T, float* __restrict__ w2T) {
  int e = blockIdx.x * 256 + threadIdx.x;
  if (e < 16384) {
    int o = e >> 8, k = e & 255;
    fwT[k * 64 + o] = fw[e];
  }
  int e2 = e - 16384;
  if (e2 >= 0 && e2 < 12288) {
    int l = e2 >> 12, r = e2 & 4095;
    int o = r >> 6, k = r & 63;
    size_t t = (size_t)l * 4096 + k * 64 + o;
    wrT[t] = rootw[e2];
    w1T[t] = lin1[e2];
    w2T[t] = lin2[e2];
  }
}

// ---------------- x -> bf16 table ----------------
__global__ __launch_bounds__(256) void convx_kernel(
    const float* __restrict__ x, uint* __restrict__ xb, int n4) {
  int e = blockIdx.x * 256 + threadIdx.x;
  if (e >= n4) return;
  float4 v = ((const float4*)x)[e];
  uint2 o;
  o.x = f2bf2(v.x, v.y);
  o.y = f2bf2(v.z, v.w);
  ((uint2*)xb)[e] = o;
}

// ---------------- CSR build: atomic-free chunked counting sort ----------------
__global__ __launch_bounds__(256) void hist_kernel(
    const int* __restrict__ src, const int* __restrict__ dst,
    int* __restrict__ Hd, int* __restrict__ Hs, int E, int N, int chunk) {
  int c = blockIdx.x, g = blockIdx.y, z = blockIdx.z;
  const int* key = z ? src : dst;
  int* H = z ? Hs : Hd;
  int lo = (int)((long long)N * g / NGRP);
  int hi = (int)((long long)N * (g + 1) / NGRP);
  int range = hi - lo;
  __shared__ int cnt[RMAX];
  for (int i = threadIdx.x; i < range; i += 256) cnt[i] = 0;
  __syncthreads();
  int e0 = c * chunk, e1 = min(E, e0 + chunk);
  for (int e = e0 + (int)threadIdx.x * 4; e < e1; e += 1024) {
    if (e + 4 <= e1) {
      int4 k4 = *(const int4*)(key + e);
      if (k4.x >= lo && k4.x < hi) atomicAdd(&cnt[k4.x - lo], 1);
      if (k4.y >= lo && k4.y < hi) atomicAdd(&cnt[k4.y - lo], 1);
      if (k4.z >= lo && k4.z < hi) atomicAdd(&cnt[k4.z - lo], 1);
      if (k4.w >= lo && k4.w < hi) atomicAdd(&cnt[k4.w - lo], 1);
    } else {
      for (int k = e; k < e1; ++k) {
        int v = key[k];
        if (v >= lo && v < hi) atomicAdd(&cnt[v - lo], 1);
      }
    }
  }
  __syncthreads();
  for (int i = threadIdx.x; i < range; i += 256)
    H[(size_t)c * N + lo + i] = cnt[i];
}

__global__ __launch_bounds__(256) void degsum_kernel(
    const int* __restrict__ Hd, const int* __restrict__ Hs,
    int* __restrict__ deg_d, int* __restrict__ deg_s, int N) {
  int n = blockIdx.x * 256 + threadIdx.x;
  if (n >= N) return;
  int sd = 0, ss = 0;
#pragma unroll
  for (int c = 0; c < NCHK; ++c) {
    sd += Hd[(size_t)c * N + n];
    ss += Hs[(size_t)c * N + n];
  }
  deg_d[n] = sd;
  deg_s[n] = ss;
}

__global__ __launch_bounds__(256) void scan_partial(
    const int* __restrict__ deg_d, const int* __restrict__ deg_s,
    int* __restrict__ bsum, int n, int nb) {
  const int* deg = (blockIdx.y == 0) ? deg_d : deg_s;
  int tid = threadIdx.x;
  int base = blockIdx.x * SCAN_ELEMS;
  int s = 0;
#pragma unroll
  for (int j = 0; j < 8; ++j) {
    int i = base + j * 256 + tid;
    if (i < n) s += deg[i];
  }
#pragma unroll
  for (int off = 1; off < 64; off <<= 1) s += __shfl_xor(s, off);
  __shared__ int ws[4];
  if ((tid & 63) == 0) ws[tid >> 6] = s;
  __syncthreads();
  if (tid == 0) bsum[blockIdx.y * nb + blockIdx.x] = ws[0] + ws[1] + ws[2] + ws[3];
}

__global__ __launch_bounds__(256) void scan_bsum(int* __restrict__ bsum, int nb) {
  __shared__ int sh[256];
  int tid = threadIdx.x;
  for (int h = 0; h < 2; ++h) {
    int v = (tid < nb) ? bsum[h * nb + tid] : 0;
    sh[tid] = v;
    __syncthreads();
    for (int off = 1; off < 256; off <<= 1) {
      int t = (tid >= off) ? sh[tid - off] : 0;
      __syncthreads();
      sh[tid] += t;
      __syncthreads();
    }
    if (tid < nb) bsum[h * nb + tid] = sh[tid] - v;  // exclusive
    __syncthreads();
  }
}

__global__ __launch_bounds__(256) void scan_final(
    const int* __restrict__ deg_d, const int* __restrict__ deg_s,
    const int* __restrict__ bsum,
    int* __restrict__ row_d, int* __restrict__ row_s, int n, int nb) {
  const int* deg = (blockIdx.y == 0) ? deg_d : deg_s;
  int* row = (blockIdx.y == 0) ? row_d : row_s;
  int tid = threadIdx.x;
  int lane = tid & 63;
  int e0 = blockIdx.x * SCAN_ELEMS + tid * 8;
  int v[8];
  int s = 0;
#pragma unroll
  for (int j = 0; j < 8; ++j) {
    int i = e0 + j;
    v[j] = (i < n) ? deg[i] : 0;
    s += v[j];
  }
  int incl = s;
#pragma unroll
  for (int off = 1; off < 64; off <<= 1) {
    int t = __shfl_up(incl, off);
    if (lane >= off) incl += t;
  }
  __shared__ int wsum[4];
  if (lane == 63) wsum[tid >> 6] = incl;
  __syncthreads();
  int woff = 0;
  int w = tid >> 6;
  for (int k = 0; k < 4; ++k)
    if (k < w) woff += wsum[k];
  int run = incl - s + woff + bsum[blockIdx.y * nb + blockIdx.x];
#pragma unroll
  for (int j = 0; j < 8; ++j) {
    int i = e0 + j;
    if (i <= n) row[i] = run;
    run += v[j];
  }
}

__global__ __launch_bounds__(256) void cursor_kernel(
    int* __restrict__ Hd, int* __restrict__ Hs,
    const int* __restrict__ row_d, const int* __restrict__ row_s, int N) {
  int n = blockIdx.x * 256 + threadIdx.x;
  if (n >= N) return;
  int rd = row_d[n], rs = row_s[n];
#pragma unroll
  for (int c = 0; c < NCHK; ++c) {
    int t = Hd[(size_t)c * N + n]; Hd[(size_t)c * N + n] = rd; rd += t;
    t = Hs[(size_t)c * N + n];     Hs[(size_t)c * N + n] = rs; rs += t;
  }
}

__global__ __launch_bounds__(256) void scatter_kernel(
    const int* __restrict__ src, const int* __restrict__ dst,
    const int* __restrict__ Hd, const int* __restrict__ Hs,
    int* __restrict__ col_d, int* __restrict__ col_s, int E, int N, int chunk) {
  int g = blockIdx.x, c = blockIdx.y, z = blockIdx.z;
  const int* key = z ? src : dst;
  const int* val = z ? dst : src;
  const int* H = z ? Hs : Hd;
  int* colp = z ? col_s : col_d;
  int lo = (int)((long long)N * g / NGRP);
  int hi = (int)((long long)N * (g + 1) / NGRP);
  int range = hi - lo;
  __shared__ int cur[RMAX];
  for (int i = threadIdx.x; i < range; i += 256)
    cur[i] = H[(size_t)c * N + lo + i];
  __syncthreads();
  int e0 = c * chunk, e1 = min(E, e0 + chunk);
  for (int e = e0 + (int)threadIdx.x * 4; e < e1; e += 1024) {
    if (e + 4 <= e1) {
      int4 k4 = *(const int4*)(key + e);
      int4 v4 = *(const int4*)(val + e);
      if (k4.x >= lo && k4.x < hi) { int p = atomicAdd(&cur[k4.x - lo], 1); colp[p] = v4.x; }
      if (k4.y >= lo && k4.y < hi) { int p = atomicAdd(&cur[k4.y - lo], 1); colp[p] = v4.y; }
      if (k4.z >= lo && k4.z < hi) { int p = atomicAdd(&cur[k4.z - lo], 1); colp[p] = v4.z; }
      if (k4.w >= lo && k4.w < hi) { int p = atomicAdd(&cur[k4.w - lo], 1); colp[p] = v4.w; }
    } else {
      for (int k = e; k < e1; ++k) {
        int kk = key[k], vv = val[k];
        if (kk >= lo && kk < hi) { int p = atomicAdd(&cur[kk - lo], 1); colp[p] = vv; }
      }
    }
  }
}

// ---------------- aggregation: 8 nodes per wave, NO cross-lane reduce --------------
// g = lane>>3 -> node slot, fl = lane&7 -> feature chunk. Degree divergence
// branch-free: loop to wave-max deg with 0/1 FMA weight + clamped col index.

#define FMA_ACC(A, U, W) {                                                   \
    A[0] += (W) * __uint_as_float((U).x << 16);                              \
    A[1] += (W) * __uint_as_float((U).x & 0xffff0000u);                      \
    A[2] += (W) * __uint_as_float((U).y << 16);                              \
    A[3] += (W) * __uint_as_float((U).y & 0xffff0000u);                      \
    A[4] += (W) * __uint_as_float((U).z << 16);                              \
    A[5] += (W) * __uint_as_float((U).z & 0xffff0000u);                      \
    A[6] += (W) * __uint_as_float((U).w << 16);                              \
    A[7] += (W) * __uint_as_float((U).w & 0xffff0000u); }

__global__ __launch_bounds__(256) void aggv_kernel(
    const ushort* __restrict__ hB,
    const int* __restrict__ row_d, const int* __restrict__ col_d, ushort* __restrict__ g1,
    const int* __restrict__ row_s, const int* __restrict__ col_s, ushort* __restrict__ g2,
    int N, int E) {
  const int* row = (blockIdx.y == 0) ? row_d : row_s;
  const int* col = (blockIdx.y == 0) ? col_d : col_s;
  ushort* outp = (blockIdx.y == 0) ? g1 : g2;
  int wv = blockIdx.x * 4 + (threadIdx.x >> 6);
  int lane = threadIdx.x & 63;
  int g = lane >> 3;
  int fl = lane & 7;
  int node = wv * 8 + g;
  int nc = min(node, N - 1);
  int s0 = row[nc], s1 = row[nc + 1];
  int d = s1 - s0;
  int dmax = d;
  dmax = max(dmax, __shfl_xor(dmax, 8));
  dmax = max(dmax, __shfl_xor(dmax, 16));
  dmax = max(dmax, __shfl_xor(dmax, 32));
  const ushort* tab = hB + fl * 8;
  float acc[8] = {0.f, 0.f, 0.f, 0.f, 0.f, 0.f, 0.f, 0.f};
  float bcc[8] = {0.f, 0.f, 0.f, 0.f, 0.f, 0.f, 0.f, 0.f};
  int i = 0;
  for (; i + 2 <= dmax; i += 2) {
    int p0 = s0 + i, p1 = s0 + i + 1;
    float w0 = p0 < s1 ? 1.f : 0.f;
    float w1 = p1 < s1 ? 1.f : 0.f;
    int n0 = col[min(p0, E - 1)];
    int n1 = col[min(p1, E - 1)];
    uint4 u0 = *(const uint4*)(tab + (size_t)n0 * 64);
    uint4 u1 = *(const uint4*)(tab + (size_t)n1 * 64);
    FMA_ACC(acc, u0, w0);
    FMA_ACC(bcc, u1, w1);
  }
  if (i < dmax) {
    int p = s0 + i;
    float w = p < s1 ? 1.f : 0.f;
    int n = col[min(p, E - 1)];
    uint4 u = *(const uint4*)(tab + (size_t)n * 64);
    FMA_ACC(acc, u, w);
  }
#pragma unroll
  for (int k = 0; k < 8; ++k) acc[k] += bcc[k];
  float inv = d > 0 ? 1.f / (float)d : 0.f;
  if (node < N) {
    uint4 o;
    o.x = f2bf2(acc[0] * inv, acc[1] * inv);
    o.y = f2bf2(acc[2] * inv, acc[3] * inv);
    o.z = f2bf2(acc[4] * inv, acc[5] * inv);
    o.w = f2bf2(acc[6] * inv, acc[7] * inv);
    *(uint4*)(outp + (size_t)node * NDIM + fl * 8) = o;
  }
}

// ---------------- combine: ONE 17KB LDS tile, 3 inputs sequenced through it ---------
// 128 nodes/block, 2 nodes/lane, wave=16 outputs. Accumulators persist across
// the h/g1/g2 passes (h@R + g1@W1 + g2@W2 grouped per-buffer). Staging loads
// issue BEFORE the WAR barrier so HBM latency hides under the previous pass.

__global__ __launch_bounds__(256, 4) void combine_kernel(
    const ushort* __restrict__ hBin, const ushort* __restrict__ g1b,
    const ushort* __restrict__ g2b, const float* __restrict__ wrT,
    const float* __restrict__ w1T, const float* __restrict__ w2T,
    const float* __restrict__ bias, ushort* __restrict__ hbout, int N) {
  __shared__ uint T[128][33];
  int tid = threadIdx.x;
  int n0 = blockIdx.x * 128;
  int r = tid >> 1, hf = tid & 1;
  int nc = min(n0 + r, N - 1);
  int w = __builtin_amdgcn_readfirstlane(tid >> 6);
  int lane = tid & 63;
  int ob = w * 16;
  float aa[16], ab[16];
#pragma unroll
  for (int o = 0; o < 16; ++o) { float bv = bias[ob + o]; aa[o] = bv; ab[o] = bv; }
  const ushort* srcs[3] = {hBin, g1b, g2b};
  const float* wts[3] = {wrT, w1T, w2T};
#pragma unroll
  for (int s = 0; s < 3; ++s) {
    const uint4* ip = (const uint4*)(srcs[s] + (size_t)nc * 64 + hf * 32);
    uint4 v0 = ip[0], v1 = ip[1], v2 = ip[2], v3 = ip[3];
    __syncthreads();                        // previous pass done reading T
    int base = hf * 16;
    T[r][base+0]=v0.x;  T[r][base+1]=v0.y;  T[r][base+2]=v0.z;  T[r][base+3]=v0.w;
    T[r][base+4]=v1.x;  T[r][base+5]=v1.y;  T[r][base+6]=v1.z;  T[r][base+7]=v1.w;
    T[r][base+8]=v2.x;  T[r][base+9]=v2.y;  T[r][base+10]=v2.z; T[r][base+11]=v2.w;
    T[r][base+12]=v3.x; T[r][base+13]=v3.y; T[r][base+14]=v3.z; T[r][base+15]=v3.w;
    __syncthreads();
    const float* wt = wts[s];
    for (int kp = 0; kp < 32; ++kp) {
      uint ua = T[lane][kp], ub = T[lane + 64][kp];
      float a0 = bflo(ua), a1 = bfhi(ua), b0 = bflo(ub), b1 = bfhi(ub);
      const float4* p0 = (const float4*)(wt + (2 * kp) * 64 + ob);
      const float4* p1 = (const float4*)(wt + (2 * kp + 1) * 64 + ob);
#pragma unroll
      for (int j = 0; j < 4; ++j) {
        float4 W0 = p0[j], W1 = p1[j];
        aa[4*j+0] += a0*W0.x + a1*W1.x;
        aa[4*j+1] += a0*W0.y + a1*W1.y;
        aa[4*j+2] += a0*W0.z + a1*W1.z;
        aa[4*j+3] += a0*W0.w + a1*W1.w;
        ab[4*j+0] += b0*W0.x + b1*W1.x;
        ab[4*j+1] += b0*W0.y + b1*W1.y;
        ab[4*j+2] += b0*W0.z + b1*W1.z;
        ab[4*j+3] += b0*W0.w + b1*W1.w;
      }
    }
  }
  int na = n0 + lane, nb = n0 + 64 + lane;
  if (na < N) {
    uint4 u0, u1;
    u0.x = f2bf2(fmaxf(aa[0],0.f),  fmaxf(aa[1],0.f));
    u0.y = f2bf2(fmaxf(aa[2],0.f),  fmaxf(aa[3],0.f));
    u0.z = f2bf2(fmaxf(aa[4],0.f),  fmaxf(aa[5],0.f));
    u0.w = f2bf2(fmaxf(aa[6],0.f),  fmaxf(aa[7],0.f));
    u1.x = f2bf2(fmaxf(aa[8],0.f),  fmaxf(aa[9],0.f));
    u1.y = f2bf2(fmaxf(aa[10],0.f), fmaxf(aa[11],0.f));
    u1.z = f2bf2(fmaxf(aa[12],0.f), fmaxf(aa[13],0.f));
    u1.w = f2bf2(fmaxf(aa[14],0.f), fmaxf(aa[15],0.f));
    uint4* op = (uint4*)(hbout + (size_t)na * NDIM + ob);
    op[0] = u0; op[1] = u1;
  }
  if (nb < N) {
    uint4 u0, u1;
    u0.x = f2bf2(fmaxf(ab[0],0.f),  fmaxf(ab[1],0.f));
    u0.y = f2bf2(fmaxf(ab[2],0.f),  fmaxf(ab[3],0.f));
    u0.z = f2bf2(fmaxf(ab[4],0.f),  fmaxf(ab[5],0.f));
    u0.w = f2bf2(fmaxf(ab[6],0.f),  fmaxf(ab[7],0.f));
    u1.x = f2bf2(fmaxf(ab[8],0.f),  fmaxf(ab[9],0.f));
    u1.y = f2bf2(fmaxf(ab[10],0.f), fmaxf(ab[11],0.f));
    u1.z = f2bf2(fmaxf(ab[12],0.f), fmaxf(ab[13],0.f));
    u1.w = f2bf2(fmaxf(ab[14],0.f), fmaxf(ab[15],0.f));
    uint4* op = (uint4*)(hbout + (size_t)nb * NDIM + ob);
    op[0] = u0; op[1] = u1;
  }
}

// ---------------- final: ONE 17KB LDS tile, 4 inputs sequenced ----------------

__global__ __launch_bounds__(256, 4) void final_kernel(
    const ushort* __restrict__ xB, const ushort* __restrict__ h1B,
    const ushort* __restrict__ h2B, const ushort* __restrict__ h3B,
    const float* __restrict__ fwT, const float* __restrict__ fb,
    float* __restrict__ outp, int N) {
  __shared__ uint T[128][33];
  int tid = threadIdx.x;
  int n0 = blockIdx.x * 128;
  int r = tid >> 1, hf = tid & 1;
  int nc = min(n0 + r, N - 1);
  int w = __builtin_amdgcn_readfirstlane(tid >> 6);
  int lane = tid & 63;
  int ob = w * 16;
  float aa[16], ab[16];
#pragma unroll
  for (int o = 0; o < 16; ++o) { float bv = fb[ob + o]; aa[o] = bv; ab[o] = bv; }
  const ushort* bufs[4] = {xB, h1B, h2B, h3B};
#pragma unroll
  for (int b = 0; b < 4; ++b) {
    const uint4* ip = (const uint4*)(bufs[b] + (size_t)nc * 64 + hf * 32);
    uint4 v0 = ip[0], v1 = ip[1], v2 = ip[2], v3 = ip[3];
    __syncthreads();
    int base = hf * 16;
    T[r][base+0]=v0.x;  T[r][base+1]=v0.y;  T[r][base+2]=v0.z;  T[r][base+3]=v0.w;
    T[r][base+4]=v1.x;  T[r][base+5]=v1.y;  T[r][base+6]=v1.z;  T[r][base+7]=v1.w;
    T[r][base+8]=v2.x;  T[r][base+9]=v2.y;  T[r][base+10]=v2.z; T[r][base+11]=v2.w;
    T[r][base+12]=v3.x; T[r][base+13]=v3.y; T[r][base+14]=v3.z; T[r][base+15]=v3.w;
    __syncthreads();
    const float* wt = fwT + (size_t)b * 64 * 64;   // k-major block for k in [64b,64b+64)
    for (int kp = 0; kp < 32; ++kp) {
      uint ua = T[lane][kp], ub = T[lane + 64][kp];
      float a0 = bflo(ua), a1 = bfhi(ua), b0 = bflo(ub), b1 = bfhi(ub);
      const float4* p0 = (const float4*)(wt + (2 * kp) * 64 + ob);
      const float4* p1 = (const float4*)(wt + (2 * kp + 1) * 64 + ob);
#pragma unroll
      for (int j = 0; j < 4; ++j) {
        float4 W0 = p0[j], W1 = p1[j];
        aa[4*j+0] += a0*W0.x + a1*W1.x;
        aa[4*j+1] += a0*W0.y + a1*W1.y;
        aa[4*j+2] += a0*W0.z + a1*W1.z;
        aa[4*j+3] += a0*W0.w + a1*W1.w;
        ab[4*j+0] += b0*W0.x + b1*W1.x;
        ab[4*j+1] += b0*W0.y + b1*W1.y;
        ab[4*j+2] += b0*W0.z + b1*W1.z;
        ab[4*j+3] += b0*W0.w + b1*W1.w;
      }
    }
  }
  int na = n0 + lane, nb = n0 + 64 + lane;
  if (na < N) {
    float4* op = (float4*)(outp + (size_t)na * NDIM + ob);
#pragma unroll
    for (int j = 0; j < 4; ++j) {
      float4 v; v.x = aa[4*j+0]; v.y = aa[4*j+1]; v.z = aa[4*j+2]; v.w = aa[4*j+3];
      op[j] = v;
    }
  }
  if (nb < N) {
    float4* op = (float4*)(outp + (size_t)nb * NDIM + ob);
#pragma unroll
    for (int j = 0; j < 4; ++j) {
      float4 v; v.x = ab[4*j+0]; v.y = ab[4*j+1]; v.z = ab[4*j+2]; v.w = ab[4*j+3];
      op[j] = v;
    }
  }
}

// ---------------- launch ----------------

extern "C" void kernel_launch(void* const* d_in, const int* in_sizes, int n_in,
                              void* d_out, int out_size, void* d_ws, size_t ws_size,
                              hipStream_t stream) {
  const float* x     = (const float*)d_in[0];
  const int*   ei    = (const int*)d_in[1];
  const float* lin1  = (const float*)d_in[2];
  const float* lin2  = (const float*)d_in[3];
  const float* rootw = (const float*)d_in[4];
  const float* rootb = (const float*)d_in[5];
  const float* fw    = (const float*)d_in[6];
  const float* fb    = (const float*)d_in[7];
  float* out = (float*)d_out;

  int N = in_sizes[0] / NDIM;
  int E = in_sizes[1] / 2;
  const int* src = ei;
  const int* dst = ei + E;

  int* ip = (int*)d_ws;
  int* Hd    = ip; ip += (size_t)NCHK * N;
  int* Hs    = ip; ip += (size_t)NCHK * N;
  int* deg_d = ip; ip += N;
  int* deg_s = ip; ip += N;
  int* row_d = ip; ip += N + 1;
  int* row_s = ip; ip += N + 1;
  int* bsum  = ip; ip += 256;
  int* col_d = ip; ip += E;
  int* col_s = ip; ip += E;
  uintptr_t fbase = (((uintptr_t)ip) + 255) & ~(uintptr_t)255;
  float* fwT = (float*)fbase;
  float* wrT = fwT + 16384;
  float* w1T = wrT + 12288;
  float* w2T = w1T + 12288;
  ushort* hB0 = (ushort*)(w2T + 12288);
  ushort* hB1 = hB0 + (size_t)N * NDIM;
  ushort* hB2 = hB1 + (size_t)N * NDIM;
  ushort* hB3 = hB2 + (size_t)N * NDIM;
  ushort* g1b = hB3 + (size_t)N * NDIM;
  ushort* g2b = g1b + (size_t)N * NDIM;

  int chunk = (E + NCHK - 1) / NCHK;
  int nb = (N + SCAN_ELEMS - 1) / SCAN_ELEMS;
  int nblk = (N + 255) / 256;

  transpose_kernel<<<112, 256, 0, stream>>>(fw, rootw, lin1, lin2, fwT, wrT, w1T, w2T);
  convx_kernel<<<(N * 16 + 255) / 256, 256, 0, stream>>>(x, (uint*)hB0, N * 16);
  hist_kernel<<<dim3(NCHK, NGRP, 2), 256, 0, stream>>>(src, dst, Hd, Hs, E, N, chunk);
  degsum_kernel<<<nblk, 256, 0, stream>>>(Hd, Hs, deg_d, deg_s, N);
  scan_partial<<<dim3(nb, 2), 256, 0, stream>>>(deg_d, deg_s, bsum, N, nb);
  scan_bsum<<<1, 256, 0, stream>>>(bsum, nb);
  scan_final<<<dim3(nb, 2), 256, 0, stream>>>(deg_d, deg_s, bsum, row_d, row_s, N, nb);
  cursor_kernel<<<nblk, 256, 0, stream>>>(Hd, Hs, row_d, row_s, N);
  scatter_kernel<<<dim3(NGRP, NCHK, 2), 256, 0, stream>>>(src, dst, Hd, Hs,
                                                          col_d, col_s, E, N, chunk);

  int avgrid = (N + 31) / 32;    // 4 waves x 8 nodes per block
  int tgrid = (N + 127) / 128;
  ushort* hBufs[4] = {hB0, hB1, hB2, hB3};
  for (int l = 0; l < 3; ++l) {
    aggv_kernel<<<dim3(avgrid, 2), 256, 0, stream>>>(hBufs[l], row_d, col_d, g1b,
                                                     row_s, col_s, g2b, N, E);
    combine_kernel<<<tgrid, 256, 0, stream>>>(hBufs[l], g1b, g2b,
                                              wrT + (size_t)l * 4096,
                                              w1T + (size_t)l * 4096,
                                              w2T + (size_t)l * 4096,
                                              rootb + (size_t)l * 64,
                                              hBufs[l + 1], N);
  }
  final_kernel<<<tgrid, 256, 0, stream>>>(hB0, hB1, hB2, hB3, fwT, fb, out, N);
}

// Round 17
// 207.608 us; speedup vs baseline: 1.5928x; 1.5928x over previous
//
#include <hip/hip_runtime.h>
#include <stdint.h>

#define NDIM 64
#define SCAN_ELEMS 2048   // elements per scan block (256 thr x 8)
#define NCHK 32           // edge chunks
#define NGRP 8            // node-range groups
#define RMAX 6272         // max nodes per group (ceil(50000/8)=6250)

typedef unsigned int uint;
typedef unsigned short ushort;
typedef __attribute__((ext_vector_type(8))) short bf16x8;
typedef __attribute__((ext_vector_type(4))) float f32x4;

// round-to-nearest-even fp32 -> bf16
__device__ __forceinline__ uint f2bf2(float a, float b) {
  uint ua = __float_as_uint(a);
  uint ub = __float_as_uint(b);
  ua += 0x7fffu + ((ua >> 16) & 1u);
  ub += 0x7fffu + ((ub >> 16) & 1u);
  return (ua >> 16) | (ub & 0xffff0000u);
}
__device__ __forceinline__ ushort f2bf1(float a) {
  uint u = __float_as_uint(a);
  u += 0x7fffu + ((u >> 16) & 1u);
  return (ushort)(u >> 16);
}

// ---------------- x -> bf16 table ----------------
__global__ __launch_bounds__(256) void convx_kernel(
    const float* __restrict__ x, uint* __restrict__ xb, int n4) {
  int e = blockIdx.x * 256 + threadIdx.x;
  if (e >= n4) return;
  float4 v = ((const float4*)x)[e];
  uint2 o;
  o.x = f2bf2(v.x, v.y);
  o.y = f2bf2(v.z, v.w);
  ((uint2*)xb)[e] = o;
}

// ---------------- weight prepack into MFMA B-fragment order (bf16) ----------------
// B-frag for mfma_f32_16x16x32_bf16: lane holds B[k][n] for k = kh*32 + (lane>>4)*8 + j,
// n = t*16 + (lane&15). cpk: [l][s][kh][t][lane][j] (12288 ushort/layer).
// fpk: [kstep][t][lane][j] (16384 ushort), k = kstep*32 + ...
__global__ __launch_bounds__(256) void prepack_kernel(
    const float* __restrict__ rootw, const float* __restrict__ lin1,
    const float* __restrict__ lin2, const float* __restrict__ fw,
    ushort* __restrict__ cpk, ushort* __restrict__ fpk) {
  int e = blockIdx.x * 256 + threadIdx.x;
  if (e < 36864) {
    int l = e / 12288;
    int e2 = e % 12288;
    int j = e2 & 7, lane = (e2 >> 3) & 63, t = (e2 >> 9) & 3;
    int kh = (e2 >> 11) & 1, s = e2 >> 12;
    int k = kh * 32 + (lane >> 4) * 8 + j;
    int o = t * 16 + (lane & 15);
    const float* mat = (s == 0) ? rootw : (s == 1) ? lin1 : lin2;
    cpk[e] = f2bf1(mat[l * 4096 + o * 64 + k]);
  } else if (e < 36864 + 16384) {
    int e3 = e - 36864;
    int j = e3 & 7, lane = (e3 >> 3) & 63, t = (e3 >> 9) & 3;
    int kstep = e3 >> 11;
    int k = kstep * 32 + (lane >> 4) * 8 + j;
    int o = t * 16 + (lane & 15);
    fpk[e3] = f2bf1(fw[o * 256 + k]);
  }
}

// ---------------- CSR build: atomic-free chunked counting sort ----------------
__global__ __launch_bounds__(256) void hist_kernel(
    const int* __restrict__ src, const int* __restrict__ dst,
    int* __restrict__ Hd, int* __restrict__ Hs, int E, int N, int chunk) {
  int c = blockIdx.x, g = blockIdx.y, z = blockIdx.z;
  const int* key = z ? src : dst;
  int* H = z ? Hs : Hd;
  int lo = (int)((long long)N * g / NGRP);
  int hi = (int)((long long)N * (g + 1) / NGRP);
  int range = hi - lo;
  __shared__ int cnt[RMAX];
  for (int i = threadIdx.x; i < range; i += 256) cnt[i] = 0;
  __syncthreads();
  int e0 = c * chunk, e1 = min(E, e0 + chunk);
  for (int e = e0 + (int)threadIdx.x * 4; e < e1; e += 1024) {
    if (e + 4 <= e1) {
      int4 k4 = *(const int4*)(key + e);
      if (k4.x >= lo && k4.x < hi) atomicAdd(&cnt[k4.x - lo], 1);
      if (k4.y >= lo && k4.y < hi) atomicAdd(&cnt[k4.y - lo], 1);
      if (k4.z >= lo && k4.z < hi) atomicAdd(&cnt[k4.z - lo], 1);
      if (k4.w >= lo && k4.w < hi) atomicAdd(&cnt[k4.w - lo], 1);
    } else {
      for (int k = e; k < e1; ++k) {
        int v = key[k];
        if (v >= lo && v < hi) atomicAdd(&cnt[v - lo], 1);
      }
    }
  }
  __syncthreads();
  for (int i = threadIdx.x; i < range; i += 256)
    H[(size_t)c * N + lo + i] = cnt[i];
}

__global__ __launch_bounds__(256) void degsum_kernel(
    const int* __restrict__ Hd, const int* __restrict__ Hs,
    int* __restrict__ deg_d, int* __restrict__ deg_s, int N) {
  int n = blockIdx.x * 256 + threadIdx.x;
  if (n >= N) return;
  int sd = 0, ss = 0;
#pragma unroll
  for (int c = 0; c < NCHK; ++c) {
    sd += Hd[(size_t)c * N + n];
    ss += Hs[(size_t)c * N + n];
  }
  deg_d[n] = sd;
  deg_s[n] = ss;
}

__global__ __launch_bounds__(256) void scan_partial(
    const int* __restrict__ deg_d, const int* __restrict__ deg_s,
    int* __restrict__ bsum, int n, int nb) {
  const int* deg = (blockIdx.y == 0) ? deg_d : deg_s;
  int tid = threadIdx.x;
  int base = blockIdx.x * SCAN_ELEMS;
  int s = 0;
#pragma unroll
  for (int j = 0; j < 8; ++j) {
    int i = base + j * 256 + tid;
    if (i < n) s += deg[i];
  }
#pragma unroll
  for (int off = 1; off < 64; off <<= 1) s += __shfl_xor(s, off);
  __shared__ int ws[4];
  if ((tid & 63) == 0) ws[tid >> 6] = s;
  __syncthreads();
  if (tid == 0) bsum[blockIdx.y * nb + blockIdx.x] = ws[0] + ws[1] + ws[2] + ws[3];
}

__global__ __launch_bounds__(256) void scan_bsum(int* __restrict__ bsum, int nb) {
  __shared__ int sh[256];
  int tid = threadIdx.x;
  for (int h = 0; h < 2; ++h) {
    int v = (tid < nb) ? bsum[h * nb + tid] : 0;
    sh[tid] = v;
    __syncthreads();
    for (int off = 1; off < 256; off <<= 1) {
      int t = (tid >= off) ? sh[tid - off] : 0;
      __syncthreads();
      sh[tid] += t;
      __syncthreads();
    }
    if (tid < nb) bsum[h * nb + tid] = sh[tid] - v;  // exclusive
    __syncthreads();
  }
}

__global__ __launch_bounds__(256) void scan_final(
    const int* __restrict__ deg_d, const int* __restrict__ deg_s,
    const int* __restrict__ bsum,
    int* __restrict__ row_d, int* __restrict__ row_s, int n, int nb) {
  const int* deg = (blockIdx.y == 0) ? deg_d : deg_s;
  int* row = (blockIdx.y == 0) ? row_d : row_s;
  int tid = threadIdx.x;
  int lane = tid & 63;
  int e0 = blockIdx.x * SCAN_ELEMS + tid * 8;
  int v[8];
  int s = 0;
#pragma unroll
  for (int j = 0; j < 8; ++j) {
    int i = e0 + j;
    v[j] = (i < n) ? deg[i] : 0;
    s += v[j];
  }
  int incl = s;
#pragma unroll
  for (int off = 1; off < 64; off <<= 1) {
    int t = __shfl_up(incl, off);
    if (lane >= off) incl += t;
  }
  __shared__ int wsum[4];
  if (lane == 63) wsum[tid >> 6] = incl;
  __syncthreads();
  int woff = 0;
  int w = tid >> 6;
  for (int k = 0; k < 4; ++k)
    if (k < w) woff += wsum[k];
  int run = incl - s + woff + bsum[blockIdx.y * nb + blockIdx.x];
#pragma unroll
  for (int j = 0; j < 8; ++j) {
    int i = e0 + j;
    if (i <= n) row[i] = run;
    run += v[j];
  }
}

__global__ __launch_bounds__(256) void cursor_kernel(
    int* __restrict__ Hd, int* __restrict__ Hs,
    const int* __restrict__ row_d, const int* __restrict__ row_s, int N) {
  int n = blockIdx.x * 256 + threadIdx.x;
  if (n >= N) return;
  int rd = row_d[n], rs = row_s[n];
#pragma unroll
  for (int c = 0; c < NCHK; ++c) {
    int t = Hd[(size_t)c * N + n]; Hd[(size_t)c * N + n] = rd; rd += t;
    t = Hs[(size_t)c * N + n];     Hs[(size_t)c * N + n] = rs; rs += t;
  }
}

__global__ __launch_bounds__(256) void scatter_kernel(
    const int* __restrict__ src, const int* __restrict__ dst,
    const int* __restrict__ Hd, const int* __restrict__ Hs,
    int* __restrict__ col_d, int* __restrict__ col_s, int E, int N, int chunk) {
  int g = blockIdx.x, c = blockIdx.y, z = blockIdx.z;
  const int* key = z ? src : dst;
  const int* val = z ? dst : src;
  const int* H = z ? Hs : Hd;
  int* colp = z ? col_s : col_d;
  int lo = (int)((long long)N * g / NGRP);
  int hi = (int)((long long)N * (g + 1) / NGRP);
  int range = hi - lo;
  __shared__ int cur[RMAX];
  for (int i = threadIdx.x; i < range; i += 256)
    cur[i] = H[(size_t)c * N + lo + i];
  __syncthreads();
  int e0 = c * chunk, e1 = min(E, e0 + chunk);
  for (int e = e0 + (int)threadIdx.x * 4; e < e1; e += 1024) {
    if (e + 4 <= e1) {
      int4 k4 = *(const int4*)(key + e);
      int4 v4 = *(const int4*)(val + e);
      if (k4.x >= lo && k4.x < hi) { int p = atomicAdd(&cur[k4.x - lo], 1); colp[p] = v4.x; }
      if (k4.y >= lo && k4.y < hi) { int p = atomicAdd(&cur[k4.y - lo], 1); colp[p] = v4.y; }
      if (k4.z >= lo && k4.z < hi) { int p = atomicAdd(&cur[k4.z - lo], 1); colp[p] = v4.z; }
      if (k4.w >= lo && k4.w < hi) { int p = atomicAdd(&cur[k4.w - lo], 1); colp[p] = v4.w; }
    } else {
      for (int k = e; k < e1; ++k) {
        int kk = key[k], vv = val[k];
        if (kk >= lo && kk < hi) { int p = atomicAdd(&cur[kk - lo], 1); colp[p] = vv; }
      }
    }
  }
}

// ---------------- aggregation: 8 nodes per wave, NO cross-lane reduce --------------

#define FMA_ACC(A, U, W) {                                                   \
    A[0] += (W) * __uint_as_float((U).x << 16);                              \
    A[1] += (W) * __uint_as_float((U).x & 0xffff0000u);                      \
    A[2] += (W) * __uint_as_float((U).y << 16);                              \
    A[3] += (W) * __uint_as_float((U).y & 0xffff0000u);                      \
    A[4] += (W) * __uint_as_float((U).z << 16);                              \
    A[5] += (W) * __uint_as_float((U).z & 0xffff0000u);                      \
    A[6] += (W) * __uint_as_float((U).w << 16);                              \
    A[7] += (W) * __uint_as_float((U).w & 0xffff0000u); }

__global__ __launch_bounds__(256) void aggv_kernel(
    const ushort* __restrict__ hB,
    const int* __restrict__ row_d, const int* __restrict__ col_d, ushort* __restrict__ g1,
    const int* __restrict__ row_s, const int* __restrict__ col_s, ushort* __restrict__ g2,
    int N, int E) {
  const int* row = (blockIdx.y == 0) ? row_d : row_s;
  const int* col = (blockIdx.y == 0) ? col_d : col_s;
  ushort* outp = (blockIdx.y == 0) ? g1 : g2;
  int wv = blockIdx.x * 4 + (threadIdx.x >> 6);
  int lane = threadIdx.x & 63;
  int g = lane >> 3;
  int fl = lane & 7;
  int node = wv * 8 + g;
  int nc = min(node, N - 1);
  int s0 = row[nc], s1 = row[nc + 1];
  int d = s1 - s0;
  int dmax = d;
  dmax = max(dmax, __shfl_xor(dmax, 8));
  dmax = max(dmax, __shfl_xor(dmax, 16));
  dmax = max(dmax, __shfl_xor(dmax, 32));
  const ushort* tab = hB + fl * 8;
  float acc[8] = {0.f, 0.f, 0.f, 0.f, 0.f, 0.f, 0.f, 0.f};
  float bcc[8] = {0.f, 0.f, 0.f, 0.f, 0.f, 0.f, 0.f, 0.f};
  int i = 0;
  for (; i + 2 <= dmax; i += 2) {
    int p0 = s0 + i, p1 = s0 + i + 1;
    float w0 = p0 < s1 ? 1.f : 0.f;
    float w1 = p1 < s1 ? 1.f : 0.f;
    int n0 = col[min(p0, E - 1)];
    int n1 = col[min(p1, E - 1)];
    uint4 u0 = *(const uint4*)(tab + (size_t)n0 * 64);
    uint4 u1 = *(const uint4*)(tab + (size_t)n1 * 64);
    FMA_ACC(acc, u0, w0);
    FMA_ACC(bcc, u1, w1);
  }
  if (i < dmax) {
    int p = s0 + i;
    float w = p < s1 ? 1.f : 0.f;
    int n = col[min(p, E - 1)];
    uint4 u = *(const uint4*)(tab + (size_t)n * 64);
    FMA_ACC(acc, u, w);
  }
#pragma unroll
  for (int k = 0; k < 8; ++k) acc[k] += bcc[k];
  float inv = d > 0 ? 1.f / (float)d : 0.f;
  if (node < N) {
    uint4 o;
    o.x = f2bf2(acc[0] * inv, acc[1] * inv);
    o.y = f2bf2(acc[2] * inv, acc[3] * inv);
    o.z = f2bf2(acc[4] * inv, acc[5] * inv);
    o.w = f2bf2(acc[6] * inv, acc[7] * inv);
    *(uint4*)(outp + (size_t)node * NDIM + fl * 8) = o;
  }
}

// ---------------- combine via MFMA: wave = 16 nodes x 64 outputs ----------------
// A-frag: lane holds act[nb + (lane&15)][k = kh*32 + (lane>>4)*8 .. +8] (one 16B load).
// B-frags prepacked. C/D: col = lane&15, row = (lane>>4)*4 + reg (guide §3, HW-verified).

__global__ __launch_bounds__(256) void combine_mfma(
    const ushort* __restrict__ hB, const ushort* __restrict__ g1b,
    const ushort* __restrict__ g2b, const ushort* __restrict__ cpkL,
    const float* __restrict__ bias, ushort* __restrict__ outB, int N) {
  int tid = threadIdx.x;
  int w = tid >> 6, lane = tid & 63;
  int col = lane & 15, kg = lane >> 4;
  int nb = blockIdx.x * 64 + w * 16;
  int arow = min(nb + col, N - 1);
  f32x4 acc[4] = {{0.f,0.f,0.f,0.f},{0.f,0.f,0.f,0.f},{0.f,0.f,0.f,0.f},{0.f,0.f,0.f,0.f}};
  const ushort* srcs[3] = {hB, g1b, g2b};
#pragma unroll
  for (int s = 0; s < 3; ++s) {
    const ushort* act = srcs[s] + (size_t)arow * 64 + kg * 8;
#pragma unroll
    for (int kh = 0; kh < 2; ++kh) {
      bf16x8 av = *(const bf16x8*)(act + kh * 32);
      const bf16x8* wb = (const bf16x8*)(cpkL + (s * 2 + kh) * 2048);
#pragma unroll
      for (int t = 0; t < 4; ++t)
        acc[t] = __builtin_amdgcn_mfma_f32_16x16x32_bf16(av, wb[t * 64 + lane], acc[t], 0, 0, 0);
    }
  }
#pragma unroll
  for (int t = 0; t < 4; ++t) {
    float bv = bias[t * 16 + col];
#pragma unroll
    for (int r = 0; r < 4; ++r) {
      int node = nb + kg * 4 + r;
      if (node < N)
        outB[(size_t)node * NDIM + t * 16 + col] = f2bf1(fmaxf(acc[t][r] + bv, 0.f));
    }
  }
}

// ---------------- final via MFMA: K=256 over 4 bf16 buffers, fp32 out ----------------

__global__ __launch_bounds__(256) void final_mfma(
    const ushort* __restrict__ xB, const ushort* __restrict__ h1B,
    const ushort* __restrict__ h2B, const ushort* __restrict__ h3B,
    const ushort* __restrict__ fpk, const float* __restrict__ fb,
    float* __restrict__ outp, int N) {
  int tid = threadIdx.x;
  int w = tid >> 6, lane = tid & 63;
  int col = lane & 15, kg = lane >> 4;
  int nb = blockIdx.x * 64 + w * 16;
  int arow = min(nb + col, N - 1);
  f32x4 acc[4] = {{0.f,0.f,0.f,0.f},{0.f,0.f,0.f,0.f},{0.f,0.f,0.f,0.f},{0.f,0.f,0.f,0.f}};
  const ushort* bufs[4] = {xB, h1B, h2B, h3B};
#pragma unroll
  for (int b = 0; b < 4; ++b) {
    const ushort* act = bufs[b] + (size_t)arow * 64 + kg * 8;
#pragma unroll
    for (int kh = 0; kh < 2; ++kh) {
      bf16x8 av = *(const bf16x8*)(act + kh * 32);
      const bf16x8* wb = (const bf16x8*)(fpk + (b * 2 + kh) * 2048);
#pragma unroll
      for (int t = 0; t < 4; ++t)
        acc[t] = __builtin_amdgcn_mfma_f32_16x16x32_bf16(av, wb[t * 64 + lane], acc[t], 0, 0, 0);
    }
  }
#pragma unroll
  for (int t = 0; t < 4; ++t) {
    float bv = fb[t * 16 + col];
#pragma unroll
    for (int r = 0; r < 4; ++r) {
      int node = nb + kg * 4 + r;
      if (node < N)
        outp[(size_t)node * NDIM + t * 16 + col] = acc[t][r] + bv;
    }
  }
}

// ---------------- launch ----------------

extern "C" void kernel_launch(void* const* d_in, const int* in_sizes, int n_in,
                              void* d_out, int out_size, void* d_ws, size_t ws_size,
                              hipStream_t stream) {
  const float* x     = (const float*)d_in[0];
  const int*   ei    = (const int*)d_in[1];
  const float* lin1  = (const float*)d_in[2];
  const float* lin2  = (const float*)d_in[3];
  const float* rootw = (const float*)d_in[4];
  const float* rootb = (const float*)d_in[5];
  const float* fw    = (const float*)d_in[6];
  const float* fb    = (const float*)d_in[7];
  float* out = (float*)d_out;

  int N = in_sizes[0] / NDIM;
  int E = in_sizes[1] / 2;
  const int* src = ei;
  const int* dst = ei + E;

  int* ip = (int*)d_ws;
  int* Hd    = ip; ip += (size_t)NCHK * N;
  int* Hs    = ip; ip += (size_t)NCHK * N;
  int* deg_d = ip; ip += N;
  int* deg_s = ip; ip += N;
  int* row_d = ip; ip += N + 1;
  int* row_s = ip; ip += N + 1;
  int* bsum  = ip; ip += 256;
  int* col_d = ip; ip += E;
  int* col_s = ip; ip += E;
  uintptr_t fbase = (((uintptr_t)ip) + 255) & ~(uintptr_t)255;
  ushort* cpk = (ushort*)fbase;            // 36864 ushorts
  ushort* fpk = cpk + 36864;               // 16384 ushorts
  ushort* hB0 = fpk + 16384;
  ushort* hB1 = hB0 + (size_t)N * NDIM;
  ushort* hB2 = hB1 + (size_t)N * NDIM;
  ushort* hB3 = hB2 + (size_t)N * NDIM;
  ushort* g1b = hB3 + (size_t)N * NDIM;
  ushort* g2b = g1b + (size_t)N * NDIM;

  int chunk = (E + NCHK - 1) / NCHK;
  int nb = (N + SCAN_ELEMS - 1) / SCAN_ELEMS;
  int nblk = (N + 255) / 256;

  convx_kernel<<<(N * 16 + 255) / 256, 256, 0, stream>>>(x, (uint*)hB0, N * 16);
  prepack_kernel<<<(36864 + 16384 + 255) / 256, 256, 0, stream>>>(
      rootw, lin1, lin2, fw, cpk, fpk);
  hist_kernel<<<dim3(NCHK, NGRP, 2), 256, 0, stream>>>(src, dst, Hd, Hs, E, N, chunk);
  degsum_kernel<<<nblk, 256, 0, stream>>>(Hd, Hs, deg_d, deg_s, N);
  scan_partial<<<dim3(nb, 2), 256, 0, stream>>>(deg_d, deg_s, bsum, N, nb);
  scan_bsum<<<1, 256, 0, stream>>>(bsum, nb);
  scan_final<<<dim3(nb, 2), 256, 0, stream>>>(deg_d, deg_s, bsum, row_d, row_s, N, nb);
  cursor_kernel<<<nblk, 256, 0, stream>>>(Hd, Hs, row_d, row_s, N);
  scatter_kernel<<<dim3(NGRP, NCHK, 2), 256, 0, stream>>>(src, dst, Hd, Hs,
                                                          col_d, col_s, E, N, chunk);

  int avgrid = (N + 31) / 32;    // 4 waves x 8 nodes per block
  int g64 = (N + 63) / 64;       // MFMA blocks: 64 nodes each
  ushort* hBufs[4] = {hB0, hB1, hB2, hB3};
  for (int l = 0; l < 3; ++l) {
    aggv_kernel<<<dim3(avgrid, 2), 256, 0, stream>>>(hBufs[l], row_d, col_d, g1b,
                                                     row_s, col_s, g2b, N, E);
    combine_mfma<<<g64, 256, 0, stream>>>(hBufs[l], g1b, g2b,
                                          cpk + (size_t)l * 12288,
                                          rootb + (size_t)l * 64,
                                          hBufs[l + 1], N);
  }
  final_mfma<<<g64, 256, 0, stream>>>(hB0, hB1, hB2, hB3, fpk, fb, out, N);
}

// Round 18
// 205.017 us; speedup vs baseline: 1.6130x; 1.0126x over previous
//
#include <hip/hip_runtime.h>
#include <stdint.h>

#define NDIM 64
#define SCAN_ELEMS 2048   // elements per scan block (256 thr x 8)
#define NCHK 32           // edge chunks
#define NGRP 8            // node-range groups (scatter: single-writer XCD per col region)
#define NGRP_H 4          // hist groups (private writes -> no ping-pong; halves read replication)
#define RMAX 6272         // ceil(50000/8)
#define RMAX_H 12544      // ceil(50000/4)

typedef unsigned int uint;
typedef unsigned short ushort;
typedef __attribute__((ext_vector_type(8))) short bf16x8;
typedef __attribute__((ext_vector_type(4))) float f32x4;

// round-to-nearest-even fp32 -> bf16
__device__ __forceinline__ uint f2bf2(float a, float b) {
  uint ua = __float_as_uint(a);
  uint ub = __float_as_uint(b);
  ua += 0x7fffu + ((ua >> 16) & 1u);
  ub += 0x7fffu + ((ub >> 16) & 1u);
  return (ua >> 16) | (ub & 0xffff0000u);
}
__device__ __forceinline__ ushort f2bf1(float a) {
  uint u = __float_as_uint(a);
  u += 0x7fffu + ((u >> 16) & 1u);
  return (ushort)(u >> 16);
}

// ---------------- x -> bf16 table ----------------
__global__ __launch_bounds__(256) void convx_kernel(
    const float* __restrict__ x, uint* __restrict__ xb, int n4) {
  int e = blockIdx.x * 256 + threadIdx.x;
  if (e >= n4) return;
  float4 v = ((const float4*)x)[e];
  uint2 o;
  o.x = f2bf2(v.x, v.y);
  o.y = f2bf2(v.z, v.w);
  ((uint2*)xb)[e] = o;
}

// ---------------- weight prepack into MFMA B-fragment order (bf16) ----------------
// B-frag for mfma_f32_16x16x32_bf16: lane holds B[k][n], k = kh*32 + (lane>>4)*8 + j,
// n = t*16 + (lane&15). cpk: [l][s][kh][t][lane][j]; fpk: [kstep][t][lane][j].
__global__ __launch_bounds__(256) void prepack_kernel(
    const float* __restrict__ rootw, const float* __restrict__ lin1,
    const float* __restrict__ lin2, const float* __restrict__ fw,
    ushort* __restrict__ cpk, ushort* __restrict__ fpk) {
  int e = blockIdx.x * 256 + threadIdx.x;
  if (e < 36864) {
    int l = e / 12288;
    int e2 = e % 12288;
    int j = e2 & 7, lane = (e2 >> 3) & 63, t = (e2 >> 9) & 3;
    int kh = (e2 >> 11) & 1, s = e2 >> 12;
    int k = kh * 32 + (lane >> 4) * 8 + j;
    int o = t * 16 + (lane & 15);
    const float* mat = (s == 0) ? rootw : (s == 1) ? lin1 : lin2;
    cpk[e] = f2bf1(mat[l * 4096 + o * 64 + k]);
  } else if (e < 36864 + 16384) {
    int e3 = e - 36864;
    int j = e3 & 7, lane = (e3 >> 3) & 63, t = (e3 >> 9) & 3;
    int kstep = e3 >> 11;
    int k = kstep * 32 + (lane >> 4) * 8 + j;
    int o = t * 16 + (lane & 15);
    fpk[e3] = f2bf1(fw[o * 256 + k]);
  }
}

// ---------------- CSR build: atomic-free chunked counting sort ----------------
__global__ __launch_bounds__(256) void hist_kernel(
    const int* __restrict__ src, const int* __restrict__ dst,
    int* __restrict__ Hd, int* __restrict__ Hs, int E, int N, int chunk) {
  int c = blockIdx.x, g = blockIdx.y, z = blockIdx.z;
  const int* key = z ? src : dst;
  int* H = z ? Hs : Hd;
  int lo = (int)((long long)N * g / NGRP_H);
  int hi = (int)((long long)N * (g + 1) / NGRP_H);
  int range = hi - lo;
  __shared__ int cnt[RMAX_H];
  for (int i = threadIdx.x; i < range; i += 256) cnt[i] = 0;
  __syncthreads();
  int e0 = c * chunk, e1 = min(E, e0 + chunk);
  for (int e = e0 + (int)threadIdx.x * 4; e < e1; e += 1024) {
    if (e + 4 <= e1) {
      int4 k4 = *(const int4*)(key + e);
      if (k4.x >= lo && k4.x < hi) atomicAdd(&cnt[k4.x - lo], 1);
      if (k4.y >= lo && k4.y < hi) atomicAdd(&cnt[k4.y - lo], 1);
      if (k4.z >= lo && k4.z < hi) atomicAdd(&cnt[k4.z - lo], 1);
      if (k4.w >= lo && k4.w < hi) atomicAdd(&cnt[k4.w - lo], 1);
    } else {
      for (int k = e; k < e1; ++k) {
        int v = key[k];
        if (v >= lo && v < hi) atomicAdd(&cnt[v - lo], 1);
      }
    }
  }
  __syncthreads();
  for (int i = threadIdx.x; i < range; i += 256)
    H[(size_t)c * N + lo + i] = cnt[i];
}

__global__ __launch_bounds__(256) void degsum_kernel(
    const int* __restrict__ Hd, const int* __restrict__ Hs,
    int* __restrict__ deg_d, int* __restrict__ deg_s, int N) {
  int n = blockIdx.x * 256 + threadIdx.x;
  if (n >= N) return;
  int sd = 0, ss = 0;
#pragma unroll
  for (int c = 0; c < NCHK; ++c) {
    sd += Hd[(size_t)c * N + n];
    ss += Hs[(size_t)c * N + n];
  }
  deg_d[n] = sd;
  deg_s[n] = ss;
}

__global__ __launch_bounds__(256) void scan_partial(
    const int* __restrict__ deg_d, const int* __restrict__ deg_s,
    int* __restrict__ bsum, int n, int nb) {
  const int* deg = (blockIdx.y == 0) ? deg_d : deg_s;
  int tid = threadIdx.x;
  int base = blockIdx.x * SCAN_ELEMS;
  int s = 0;
#pragma unroll
  for (int j = 0; j < 8; ++j) {
    int i = base + j * 256 + tid;
    if (i < n) s += deg[i];
  }
#pragma unroll
  for (int off = 1; off < 64; off <<= 1) s += __shfl_xor(s, off);
  __shared__ int ws[4];
  if ((tid & 63) == 0) ws[tid >> 6] = s;
  __syncthreads();
  if (tid == 0) bsum[blockIdx.y * nb + blockIdx.x] = ws[0] + ws[1] + ws[2] + ws[3];
}

__global__ __launch_bounds__(256) void scan_bsum(int* __restrict__ bsum, int nb) {
  __shared__ int sh[256];
  int tid = threadIdx.x;
  for (int h = 0; h < 2; ++h) {
    int v = (tid < nb) ? bsum[h * nb + tid] : 0;
    sh[tid] = v;
    __syncthreads();
    for (int off = 1; off < 256; off <<= 1) {
      int t = (tid >= off) ? sh[tid - off] : 0;
      __syncthreads();
      sh[tid] += t;
      __syncthreads();
    }
    if (tid < nb) bsum[h * nb + tid] = sh[tid] - v;  // exclusive
    __syncthreads();
  }
}

__global__ __launch_bounds__(256) void scan_final(
    const int* __restrict__ deg_d, const int* __restrict__ deg_s,
    const int* __restrict__ bsum,
    int* __restrict__ row_d, int* __restrict__ row_s, int n, int nb) {
  const int* deg = (blockIdx.y == 0) ? deg_d : deg_s;
  int* row = (blockIdx.y == 0) ? row_d : row_s;
  int tid = threadIdx.x;
  int lane = tid & 63;
  int e0 = blockIdx.x * SCAN_ELEMS + tid * 8;
  int v[8];
  int s = 0;
#pragma unroll
  for (int j = 0; j < 8; ++j) {
    int i = e0 + j;
    v[j] = (i < n) ? deg[i] : 0;
    s += v[j];
  }
  int incl = s;
#pragma unroll
  for (int off = 1; off < 64; off <<= 1) {
    int t = __shfl_up(incl, off);
    if (lane >= off) incl += t;
  }
  __shared__ int wsum[4];
  if (lane == 63) wsum[tid >> 6] = incl;
  __syncthreads();
  int woff = 0;
  int w = tid >> 6;
  for (int k = 0; k < 4; ++k)
    if (k < w) woff += wsum[k];
  int run = incl - s + woff + bsum[blockIdx.y * nb + blockIdx.x];
#pragma unroll
  for (int j = 0; j < 8; ++j) {
    int i = e0 + j;
    if (i <= n) row[i] = run;
    run += v[j];
  }
}

__global__ __launch_bounds__(256) void cursor_kernel(
    int* __restrict__ Hd, int* __restrict__ Hs,
    const int* __restrict__ row_d, const int* __restrict__ row_s, int N) {
  int n = blockIdx.x * 256 + threadIdx.x;
  if (n >= N) return;
  int rd = row_d[n], rs = row_s[n];
#pragma unroll
  for (int c = 0; c < NCHK; ++c) {
    int t = Hd[(size_t)c * N + n]; Hd[(size_t)c * N + n] = rd; rd += t;
    t = Hs[(size_t)c * N + n];     Hs[(size_t)c * N + n] = rs; rs += t;
  }
}

// scatter: grid (g=NGRP, c, z) -> linear%8 = g -> single-writer XCD per col
// region. col arrays are ushort (node ids < 65536).
__global__ __launch_bounds__(256) void scatter_kernel(
    const int* __restrict__ src, const int* __restrict__ dst,
    const int* __restrict__ Hd, const int* __restrict__ Hs,
    ushort* __restrict__ col_d, ushort* __restrict__ col_s, int E, int N, int chunk) {
  int g = blockIdx.x, c = blockIdx.y, z = blockIdx.z;
  const int* key = z ? src : dst;
  const int* val = z ? dst : src;
  const int* H = z ? Hs : Hd;
  ushort* colp = z ? col_s : col_d;
  int lo = (int)((long long)N * g / NGRP);
  int hi = (int)((long long)N * (g + 1) / NGRP);
  int range = hi - lo;
  __shared__ int cur[RMAX];
  for (int i = threadIdx.x; i < range; i += 256)
    cur[i] = H[(size_t)c * N + lo + i];
  __syncthreads();
  int e0 = c * chunk, e1 = min(E, e0 + chunk);
  for (int e = e0 + (int)threadIdx.x * 4; e < e1; e += 1024) {
    if (e + 4 <= e1) {
      int4 k4 = *(const int4*)(key + e);
      int4 v4 = *(const int4*)(val + e);
      if (k4.x >= lo && k4.x < hi) { int p = atomicAdd(&cur[k4.x - lo], 1); colp[p] = (ushort)v4.x; }
      if (k4.y >= lo && k4.y < hi) { int p = atomicAdd(&cur[k4.y - lo], 1); colp[p] = (ushort)v4.y; }
      if (k4.z >= lo && k4.z < hi) { int p = atomicAdd(&cur[k4.z - lo], 1); colp[p] = (ushort)v4.z; }
      if (k4.w >= lo && k4.w < hi) { int p = atomicAdd(&cur[k4.w - lo], 1); colp[p] = (ushort)v4.w; }
    } else {
      for (int k = e; k < e1; ++k) {
        int kk = key[k], vv = val[k];
        if (kk >= lo && kk < hi) { int p = atomicAdd(&cur[kk - lo], 1); colp[p] = (ushort)vv; }
      }
    }
  }
}

// ---------------- aggregation: 8 nodes per wave, NO cross-lane reduce --------------
// g = lane>>3 -> node slot, fl = lane&7 -> feature chunk. Degree divergence
// branch-free: loop to wave-max deg with 0/1 FMA weight + clamped col index.

#define FMA_ACC(A, U, W) {                                                   \
    A[0] += (W) * __uint_as_float((U).x << 16);                              \
    A[1] += (W) * __uint_as_float((U).x & 0xffff0000u);                      \
    A[2] += (W) * __uint_as_float((U).y << 16);                              \
    A[3] += (W) * __uint_as_float((U).y & 0xffff0000u);                      \
    A[4] += (W) * __uint_as_float((U).z << 16);                              \
    A[5] += (W) * __uint_as_float((U).z & 0xffff0000u);                      \
    A[6] += (W) * __uint_as_float((U).w << 16);                              \
    A[7] += (W) * __uint_as_float((U).w & 0xffff0000u); }

__global__ __launch_bounds__(256) void aggv_kernel(
    const ushort* __restrict__ hB,
    const int* __restrict__ row_d, const ushort* __restrict__ col_d, ushort* __restrict__ g1,
    const int* __restrict__ row_s, const ushort* __restrict__ col_s, ushort* __restrict__ g2,
    int N, int E) {
  const int* row = (blockIdx.y == 0) ? row_d : row_s;
  const ushort* col = (blockIdx.y == 0) ? col_d : col_s;
  ushort* outp = (blockIdx.y == 0) ? g1 : g2;
  int wv = blockIdx.x * 4 + (threadIdx.x >> 6);
  int lane = threadIdx.x & 63;
  int g = lane >> 3;
  int fl = lane & 7;
  int node = wv * 8 + g;
  int nc = min(node, N - 1);
  int s0 = row[nc], s1 = row[nc + 1];
  int d = s1 - s0;
  int dmax = d;
  dmax = max(dmax, __shfl_xor(dmax, 8));
  dmax = max(dmax, __shfl_xor(dmax, 16));
  dmax = max(dmax, __shfl_xor(dmax, 32));
  const ushort* tab = hB + fl * 8;
  float acc[8] = {0.f, 0.f, 0.f, 0.f, 0.f, 0.f, 0.f, 0.f};
  float bcc[8] = {0.f, 0.f, 0.f, 0.f, 0.f, 0.f, 0.f, 0.f};
  int i = 0;
  for (; i + 2 <= dmax; i += 2) {
    int p0 = s0 + i, p1 = s0 + i + 1;
    float w0 = p0 < s1 ? 1.f : 0.f;
    float w1 = p1 < s1 ? 1.f : 0.f;
    int n0 = col[min(p0, E - 1)];
    int n1 = col[min(p1, E - 1)];
    uint4 u0 = *(const uint4*)(tab + (size_t)n0 * 64);
    uint4 u1 = *(const uint4*)(tab + (size_t)n1 * 64);
    FMA_ACC(acc, u0, w0);
    FMA_ACC(bcc, u1, w1);
  }
  if (i < dmax) {
    int p = s0 + i;
    float w = p < s1 ? 1.f : 0.f;
    int n = col[min(p, E - 1)];
    uint4 u = *(const uint4*)(tab + (size_t)n * 64);
    FMA_ACC(acc, u, w);
  }
#pragma unroll
  for (int k = 0; k < 8; ++k) acc[k] += bcc[k];
  float inv = d > 0 ? 1.f / (float)d : 0.f;
  if (node < N) {
    uint4 o;
    o.x = f2bf2(acc[0] * inv, acc[1] * inv);
    o.y = f2bf2(acc[2] * inv, acc[3] * inv);
    o.z = f2bf2(acc[4] * inv, acc[5] * inv);
    o.w = f2bf2(acc[6] * inv, acc[7] * inv);
    *(uint4*)(outp + (size_t)node * NDIM + fl * 8) = o;
  }
}

// ---------------- combine via MFMA: wave = 16 nodes x 64 outputs ----------------
__global__ __launch_bounds__(256) void combine_mfma(
    const ushort* __restrict__ hB, const ushort* __restrict__ g1b,
    const ushort* __restrict__ g2b, const ushort* __restrict__ cpkL,
    const float* __restrict__ bias, ushort* __restrict__ outB, int N) {
  int tid = threadIdx.x;
  int w = tid >> 6, lane = tid & 63;
  int col = lane & 15, kg = lane >> 4;
  int nb = blockIdx.x * 64 + w * 16;
  int arow = min(nb + col, N - 1);
  f32x4 acc[4] = {{0.f,0.f,0.f,0.f},{0.f,0.f,0.f,0.f},{0.f,0.f,0.f,0.f},{0.f,0.f,0.f,0.f}};
  const ushort* srcs[3] = {hB, g1b, g2b};
#pragma unroll
  for (int s = 0; s < 3; ++s) {
    const ushort* act = srcs[s] + (size_t)arow * 64 + kg * 8;
#pragma unroll
    for (int kh = 0; kh < 2; ++kh) {
      bf16x8 av = *(const bf16x8*)(act + kh * 32);
      const bf16x8* wb = (const bf16x8*)(cpkL + (s * 2 + kh) * 2048);
#pragma unroll
      for (int t = 0; t < 4; ++t)
        acc[t] = __builtin_amdgcn_mfma_f32_16x16x32_bf16(av, wb[t * 64 + lane], acc[t], 0, 0, 0);
    }
  }
#pragma unroll
  for (int t = 0; t < 4; ++t) {
    float bv = bias[t * 16 + col];
#pragma unroll
    for (int r = 0; r < 4; ++r) {
      int node = nb + kg * 4 + r;
      if (node < N)
        outB[(size_t)node * NDIM + t * 16 + col] = f2bf1(fmaxf(acc[t][r] + bv, 0.f));
    }
  }
}

// ---------------- final via MFMA: K=256 over 4 bf16 buffers, fp32 out ----------------
__global__ __launch_bounds__(256) void final_mfma(
    const ushort* __restrict__ xB, const ushort* __restrict__ h1B,
    const ushort* __restrict__ h2B, const ushort* __restrict__ h3B,
    const ushort* __restrict__ fpk, const float* __restrict__ fb,
    float* __restrict__ outp, int N) {
  int tid = threadIdx.x;
  int w = tid >> 6, lane = tid & 63;
  int col = lane & 15, kg = lane >> 4;
  int nb = blockIdx.x * 64 + w * 16;
  int arow = min(nb + col, N - 1);
  f32x4 acc[4] = {{0.f,0.f,0.f,0.f},{0.f,0.f,0.f,0.f},{0.f,0.f,0.f,0.f},{0.f,0.f,0.f,0.f}};
  const ushort* bufs[4] = {xB, h1B, h2B, h3B};
#pragma unroll
  for (int b = 0; b < 4; ++b) {
    const ushort* act = bufs[b] + (size_t)arow * 64 + kg * 8;
#pragma unroll
    for (int kh = 0; kh < 2; ++kh) {
      bf16x8 av = *(const bf16x8*)(act + kh * 32);
      const bf16x8* wb = (const bf16x8*)(fpk + (b * 2 + kh) * 2048);
#pragma unroll
      for (int t = 0; t < 4; ++t)
        acc[t] = __builtin_amdgcn_mfma_f32_16x16x32_bf16(av, wb[t * 64 + lane], acc[t], 0, 0, 0);
    }
  }
#pragma unroll
  for (int t = 0; t < 4; ++t) {
    float bv = fb[t * 16 + col];
#pragma unroll
    for (int r = 0; r < 4; ++r) {
      int node = nb + kg * 4 + r;
      if (node < N)
        outp[(size_t)node * NDIM + t * 16 + col] = acc[t][r] + bv;
    }
  }
}

// ---------------- launch ----------------

extern "C" void kernel_launch(void* const* d_in, const int* in_sizes, int n_in,
                              void* d_out, int out_size, void* d_ws, size_t ws_size,
                              hipStream_t stream) {
  const float* x     = (const float*)d_in[0];
  const int*   ei    = (const int*)d_in[1];
  const float* lin1  = (const float*)d_in[2];
  const float* lin2  = (const float*)d_in[3];
  const float* rootw = (const float*)d_in[4];
  const float* rootb = (const float*)d_in[5];
  const float* fw    = (const float*)d_in[6];
  const float* fb    = (const float*)d_in[7];
  float* out = (float*)d_out;

  int N = in_sizes[0] / NDIM;
  int E = in_sizes[1] / 2;
  const int* src = ei;
  const int* dst = ei + E;

  int* ip = (int*)d_ws;
  int* Hd    = ip; ip += (size_t)NCHK * N;
  int* Hs    = ip; ip += (size_t)NCHK * N;
  int* deg_d = ip; ip += N;
  int* deg_s = ip; ip += N;
  int* row_d = ip; ip += N + 1;
  int* row_s = ip; ip += N + 1;
  int* bsum  = ip; ip += 256;
  ushort* col_d = (ushort*)ip; ip += (E + 1) / 2;
  ushort* col_s = (ushort*)ip; ip += (E + 1) / 2;
  uintptr_t fbase = (((uintptr_t)ip) + 255) & ~(uintptr_t)255;
  ushort* cpk = (ushort*)fbase;            // 36864 ushorts
  ushort* fpk = cpk + 36864;               // 16384 ushorts
  ushort* hB0 = fpk + 16384;
  ushort* hB1 = hB0 + (size_t)N * NDIM;
  ushort* hB2 = hB1 + (size_t)N * NDIM;
  ushort* hB3 = hB2 + (size_t)N * NDIM;
  ushort* g1b = hB3 + (size_t)N * NDIM;
  ushort* g2b = g1b + (size_t)N * NDIM;

  int chunk = (E + NCHK - 1) / NCHK;
  int nb = (N + SCAN_ELEMS - 1) / SCAN_ELEMS;
  int nblk = (N + 255) / 256;

  convx_kernel<<<(N * 16 + 255) / 256, 256, 0, stream>>>(x, (uint*)hB0, N * 16);
  prepack_kernel<<<(36864 + 16384 + 255) / 256, 256, 0, stream>>>(
      rootw, lin1, lin2, fw, cpk, fpk);
  hist_kernel<<<dim3(NCHK, NGRP_H, 2), 256, 0, stream>>>(src, dst, Hd, Hs, E, N, chunk);
  degsum_kernel<<<nblk, 256, 0, stream>>>(Hd, Hs, deg_d, deg_s, N);
  scan_partial<<<dim3(nb, 2), 256, 0, stream>>>(deg_d, deg_s, bsum, N, nb);
  scan_bsum<<<1, 256, 0, stream>>>(bsum, nb);
  scan_final<<<dim3(nb, 2), 256, 0, stream>>>(deg_d, deg_s, bsum, row_d, row_s, N, nb);
  cursor_kernel<<<nblk, 256, 0, stream>>>(Hd, Hs, row_d, row_s, N);
  scatter_kernel<<<dim3(NGRP, NCHK, 2), 256, 0, stream>>>(src, dst, Hd, Hs,
                                                          col_d, col_s, E, N, chunk);

  int avgrid = (N + 31) / 32;    // 4 waves x 8 nodes per block
  int g64 = (N + 63) / 64;       // MFMA blocks: 64 nodes each
  ushort* hBufs[4] = {hB0, hB1, hB2, hB3};
  for (int l = 0; l < 3; ++l) {
    aggv_kernel<<<dim3(avgrid, 2), 256, 0, stream>>>(hBufs[l], row_d, col_d, g1b,
                                                     row_s, col_s, g2b, N, E);
    combine_mfma<<<g64, 256, 0, stream>>>(hBufs[l], g1b, g2b,
                                          cpk + (size_t)l * 12288,
                                          rootb + (size_t)l * 64,
                                          hBufs[l + 1], N);
  }
  final_mfma<<<g64, 256, 0, stream>>>(hB0, hB1, hB2, hB3, fpk, fb, out, N);
}